// Round 3
// baseline (251.290 us; speedup 1.0000x reference)
//
#include <hip/hip_runtime.h>
#include <stdint.h>

#define D_DIM 784
#define H_DIM 1024
#define B_DIM 256
#define NBIN  10
#define G_CH  8             // chunk length (i's per main block)
#define T_CH  98            // D_DIM / G_CH
#define BT    16            // batch tile per main block (fixed by MFMA M=16)
#define LOG2E 1.4426950408889634f

#define PSCAN_BLKS 512      // 64 batch-quads x 2 h-groups x 4 t-quarters
#define VPREP_BLKS D_DIM    // 784
#define WPREP_BLKS 208      // 13 * 16 tiles of W transpose

typedef _Float16 half8_t  __attribute__((ext_vector_type(8)));
typedef __fp16   fp16x2_t __attribute__((ext_vector_type(2)));
typedef float    float4_t __attribute__((ext_vector_type(4)));

// ---------------------------------------------------------------------------
// k_prep2: ONE dispatch, three independent jobs:
//   blocks [0,512)        : prefix-scan PA. 4-way t-split (redundant prefix
//                           recompute, no cross-block deps), 4 b x 2 h per
//                           thread, checkpoint-in-registers + burst stores
//                           (no store-retire stall in the FMA chain).
//   blocks [512,1296)     : V -> VB MFMA-fragment reshape, 2 passes of 512 h
//   blocks [1296,1504)    : W -> Wt2h f16 transpose (x LOG2E)
// ---------------------------------------------------------------------------
__global__ void k_prep2(const float* __restrict__ W, const float* __restrict__ V,
                        const float* __restrict__ c, const int* __restrict__ x,
                        _Float16* __restrict__ Wt2h, _Float16* __restrict__ VB,
                        _Float16* __restrict__ PA) {
    __shared__ __align__(16) float smem[5120];   // 20 KB, aliased by all branches
    int tid = threadIdx.x;
    int bx  = blockIdx.x;

    if (bx < PSCAN_BLKS) {
        int bp = bx & 63;             // batch quad 0..63
        int hg = (bx >> 6) & 1;       // h-group 0..1
        int tg = 3 - (bx >> 7);       // t-quarter, longest (tg=3) dispatched first
        int b0 = bp * 4;
        int h0 = hg * 512 + tid * 2;  // this thread owns h0, h0+1
        float (*xs)[D_DIM] = (float(*)[D_DIM])smem;   // [4][784] = 12.5 KB
        for (int qq = tid; qq < 4 * (D_DIM / 4); qq += 256) {
            int bb = qq / (D_DIM / 4), r = qq % (D_DIM / 4);
            int4 xi = ((const int4*)(x + (size_t)(b0 + bb) * D_DIM))[r];
            *((float4*)&xs[bb][r * 4]) =
                make_float4((float)xi.x, (float)xi.y, (float)xi.z, (float)xi.w);
        }
        float c0 = c[h0], c1 = c[h0 + 1];
        float a0[4], a1[4];           // a0[b]: h0 col, a1[b]: h0+1 col
        #pragma unroll
        for (int b = 0; b < 4; ++b) { a0[b] = c0; a1[b] = c1; }
        __syncthreads();
        const float4* w0 = (const float4*)(W + (size_t)h0 * D_DIM);
        const float4* w1 = (const float4*)(W + (size_t)(h0 + 1) * D_DIM);
        uint* pau = (uint*)PA;
        int hcol = hg * 256 + tid;
        int t0 = tg * 25;

        auto fma8 = [&](int t, float4 wa, float4 wb, float4 wc, float4 wd) {
            #pragma unroll
            for (int b = 0; b < 4; ++b) {
                float4 xA = *((const float4*)&xs[b][t * 8]);
                float4 xB = *((const float4*)&xs[b][t * 8 + 4]);
                a0[b] += xA.x*wa.x + xA.y*wa.y + xA.z*wa.z + xA.w*wa.w
                       + xB.x*wb.x + xB.y*wb.y + xB.z*wb.z + xB.w*wb.w;
                a1[b] += xA.x*wc.x + xA.y*wc.y + xA.z*wc.z + xA.w*wc.w
                       + xB.x*wd.x + xB.y*wd.y + xB.z*wd.z + xB.w*wd.w;
            }
        };

        // phase A: redundant prefix accumulate, no stores (pure FMA + L2 reads)
        #pragma unroll 2
        for (int t = 0; t < t0; ++t)
            fma8(t, w0[2*t], w0[2*t+1], w1[2*t], w1[2*t+1]);

        // phase B: 5 sub-bursts of 5 checkpoints; stores only between bursts
        #pragma unroll
        for (int bo = 0; bo < 5; ++bo) {
            uint chk[5][4];           // statically indexed (stays in VGPRs)
            #pragma unroll
            for (int k = 0; k < 5; ++k) {
                int t = t0 + bo * 5 + k;
                if (t < T_CH) {
                    #pragma unroll
                    for (int b = 0; b < 4; ++b) {
                        union { _Float16 hh[2]; uint u; } uu;
                        uu.hh[0] = (_Float16)(a0[b] * LOG2E);
                        uu.hh[1] = (_Float16)(a1[b] * LOG2E);
                        chk[k][b] = uu.u;
                    }
                    fma8(t, w0[2*t], w0[2*t+1], w1[2*t], w1[2*t+1]);
                }
            }
            #pragma unroll
            for (int k = 0; k < 5; ++k) {
                int t = t0 + bo * 5 + k;
                if (t < T_CH) {
                    #pragma unroll
                    for (int b = 0; b < 4; ++b)
                        pau[((size_t)t * B_DIM + b0 + b) * 512 + hcol] = chk[k][b];
                }
            }
        }
    } else if (bx < PSCAN_BLKS + VPREP_BLKS) {
        // ---- V -> VB fragment reshape, 2 passes of 512 h (20 KB each) ----
        int i = bx - PSCAN_BLKS;
        const float4* src = (const float4*)(V + (size_t)i * H_DIM * NBIN);
        uint4* dst = (uint4*)VB + (size_t)i * 2048;
        #pragma unroll
        for (int p = 0; p < 2; ++p) {
            if (p) __syncthreads();               // pass-0 consumers done
            #pragma unroll
            for (int qv = 0; qv < 5; ++qv) {
                float4 v = src[p * 1280 + qv * 256 + tid];
                *((float4*)&smem[(qv * 256 + tid) * 4]) = v;
            }
            __syncthreads();
            #pragma unroll
            for (int qv = 0; qv < 4; ++qv) {
                int pair = p * 1024 + qv * 256 + tid;  // (kk,l) pair
                int kk = pair >> 6, ll = pair & 63;
                int n = ll & 15, hb = kk * 32 + ((ll >> 4) & 3) * 8;
                union { _Float16 hh[8]; uint4 u; } o;
                #pragma unroll
                for (int jj = 0; jj < 8; ++jj)
                    o.hh[jj] = (_Float16)((n < NBIN) ? smem[(hb + jj) * NBIN + n - p * 5120] : 0.0f);
                dst[pair] = o.u;
            }
        }
    } else {
        // ---- W transpose -> Wt2h (f16, x LOG2E) ----
        int qw = bx - PSCAN_BLKS - VPREP_BLKS;  // 0..207
        int j0 = (qw % 13) * 64, h0 = (qw / 13) * 64;
        float (*t)[65] = (float(*)[65])smem;    // 16.6 KB view (fits in 20 KB)
        int tj = tid & 63, tr = tid >> 6;
        int j = j0 + tj;
        #pragma unroll
        for (int r = 0; r < 16; ++r) {
            int hh = tr * 16 + r;
            t[hh][tj] = (j < D_DIM) ? W[(size_t)(h0 + hh) * D_DIM + j] : 0.0f;
        }
        __syncthreads();
        #pragma unroll
        for (int r = 0; r < 16; ++r) {
            int jj = tr * 16 + r;
            int jo = j0 + jj;
            if (jo < D_DIM) Wt2h[(size_t)jo * H_DIM + h0 + tj] = (_Float16)(t[tj][jj] * LOG2E);
        }
    }
}

// ---------------------------------------------------------------------------
// main fused kernel: rolling 3-slot VB prefetch, streamed cf flush (low VGPR),
// launch_bounds(256,4) -> 4 blocks/CU (LDS 35.3 KB x 4 = 141 KB fits).
// (unchanged from previous round for clean attribution)
// ---------------------------------------------------------------------------
__global__ __launch_bounds__(256, 4)
void k_main(const _Float16* __restrict__ VB, const _Float16* __restrict__ Wt2h,
            const _Float16* __restrict__ PA, const int* __restrict__ x,
            const float* __restrict__ bias, float* __restrict__ out) {
    int bt  = blockIdx.x;        // batch tile 0..15 (fast dim: VB L2 reuse)
    int tc  = blockIdx.y;        // chunk 0..97
    int tid = threadIdx.x;
    int w   = tid >> 6;          // wave 0..3 (K-split of H)
    int l   = tid & 63;
    int bl  = l & 15;            // MFMA A row == batch row within tile
    int kg  = l >> 4;            // 0..3
    int bg  = bt * BT + bl;
    int i0  = tc * G_CH;

    __shared__ __align__(16) _Float16 wlds[G_CH][H_DIM]; // 16 KB
    __shared__ float red[4][64][18];                     // 18.4 KB, stride-18: 2-way max (free)
    __shared__ float bs[G_CH][16];                       // 0.5 KB

    {   // stage bias chunk
        int ii = tid >> 4, n = tid & 15;
        if (ii < G_CH) bs[ii][n] = (n < NBIN) ? bias[(size_t)(i0 + ii) * NBIN + n] : 0.0f;
    }
    {   // stage Wt2h chunk rows i0..i0+7 (f16 direct copy, coalesced)
        #pragma unroll
        for (int r = 0; r < G_CH; ++r) {
            uint2 v = ((const uint2*)(Wt2h + (size_t)(i0 + r) * H_DIM))[tid];
            *((uint2*)&wlds[r][tid * 4]) = v;
        }
    }
    float xvf[G_CH];
    {
        const int4* xp = (const int4*)(x + (size_t)bg * D_DIM + i0);
        int4 x0 = xp[0], x1 = xp[1];
        xvf[0] = (float)x0.x; xvf[1] = (float)x0.y; xvf[2] = (float)x0.z; xvf[3] = (float)x0.w;
        xvf[4] = (float)x1.x; xvf[5] = (float)x1.y; xvf[6] = (float)x1.z; xvf[7] = (float)x1.w;
    }
    float a[8][8];
    {
        const _Float16* src = PA + ((size_t)tc * B_DIM + bg) * H_DIM + w * 256 + kg * 8;
        #pragma unroll
        for (int m = 0; m < 8; ++m) {
            half8_t av = *((const half8_t*)(src + m * 32));
            #pragma unroll
            for (int j = 0; j < 8; ++j) a[m][j] = (float)av[j];
        }
    }

    // rolling 3-slot VB prefetch: slot mm%3 used at step mm, refilled for mm+2
    const uint4* vp = (const uint4*)VB + ((size_t)i0 * 32 + w * 8) * 64 + l;
    uint4 vbuf[3];
    vbuf[0] = vp[0];                 // (ii=0, m=0)
    vbuf[1] = vp[64];                // (ii=0, m=1)
    float4_t acc = {0.f, 0.f, 0.f, 0.f};

    auto step = [&](int mm) {        // mm = ii*8 + m, all indices static after unroll
        const int ii = mm >> 3, m = mm & 7;
        if (mm + 2 < 64) {
            const int nn = mm + 2;
            vbuf[nn % 3] = vp[((nn >> 3) * 32 + (nn & 7)) * 64];
        }
        union { half8_t h8; uint u32[4]; } af;
        #pragma unroll
        for (int p = 0; p < 4; ++p) {
            float s0 = __builtin_amdgcn_rcpf(1.0f + __builtin_amdgcn_exp2f(-a[m][2 * p]));
            float s1 = __builtin_amdgcn_rcpf(1.0f + __builtin_amdgcn_exp2f(-a[m][2 * p + 1]));
            union { fp16x2_t v; uint u; } cv;
            cv.v = __builtin_amdgcn_cvt_pkrtz(s0, s1);
            af.u32[p] = cv.u;
        }
        union { half8_t h8; uint4 u; } bf;
        bf.u = vbuf[mm % 3];
        acc = __builtin_amdgcn_mfma_f32_16x16x32_f16(af.h8, bf.h8, acc, 0, 0, 0);
        half8_t wh = *((const half8_t*)&wlds[ii][w * 256 + kg * 8 + m * 32]);
        float xf = xvf[ii];
        a[m][0] += xf * (float)wh[0]; a[m][1] += xf * (float)wh[1];
        a[m][2] += xf * (float)wh[2]; a[m][3] += xf * (float)wh[3];
        a[m][4] += xf * (float)wh[4]; a[m][5] += xf * (float)wh[5];
        a[m][6] += xf * (float)wh[6]; a[m][7] += xf * (float)wh[7];
        if (m == 7) {                // stream flush: keeps only ONE float4 acc live
            int s = (ii & 3) * 4;
            red[w][l][s + 0] = acc[0]; red[w][l][s + 1] = acc[1];
            red[w][l][s + 2] = acc[2]; red[w][l][s + 3] = acc[3];
            acc = (float4_t){0.f, 0.f, 0.f, 0.f};
        }
    };

    auto softmax_store = [&](int half) {
        float p4[4];
        #pragma unroll
        for (int q = 0; q < 4; ++q) {
            int ii = half * 4 + q;
            float tot = red[0][l][q * 4 + w] + red[1][l][q * 4 + w]
                      + red[2][l][q * 4 + w] + red[3][l][q * 4 + w];
            float v = (bl < NBIN) ? tot + bs[ii][bl] : -3.0e38f;
            float vm = v;
            vm = fmaxf(vm, __shfl_xor(vm, 1));
            vm = fmaxf(vm, __shfl_xor(vm, 2));
            vm = fmaxf(vm, __shfl_xor(vm, 4));
            vm = fmaxf(vm, __shfl_xor(vm, 8));
            float e = __builtin_amdgcn_exp2f((v - vm) * LOG2E);
            float ss = e;
            ss += __shfl_xor(ss, 1); ss += __shfl_xor(ss, 2);
            ss += __shfl_xor(ss, 4); ss += __shfl_xor(ss, 8);
            p4[q] = e * __builtin_amdgcn_rcpf(ss);
        }
        if (bl < NBIN) {
            int b = bt * BT + kg * 4 + w;   // this thread's C row = batch row
            size_t base = ((size_t)b * NBIN + bl) * D_DIM + i0 + half * 4;
            float4 v = make_float4(p4[0], p4[1], p4[2], p4[3]);
            *((float4*)(out + base)) = v;
        }
    };

    __syncthreads();               // B0: wlds/bs staged
    #pragma unroll
    for (int mm = 0; mm < 32; ++mm) step(mm);     // half 0 (red streamed)
    __syncthreads();               // B1: half-0 partials visible
    softmax_store(0);
    __syncthreads();               // B2: all half-0 reads done
    #pragma unroll
    for (int mm = 32; mm < 64; ++mm) step(mm);    // half 1 (red streamed)
    __syncthreads();               // B3: half-1 partials visible
    softmax_store(1);
}

extern "C" void kernel_launch(void* const* d_in, const int* in_sizes, int n_in,
                              void* d_out, int out_size, void* d_ws, size_t ws_size,
                              hipStream_t stream) {
    const int*   x    = (const int*)d_in[0];
    const float* W    = (const float*)d_in[1];
    const float* c    = (const float*)d_in[2];
    const float* V    = (const float*)d_in[3];
    const float* bias = (const float*)d_in[4];
    float* out = (float*)d_out;

    char* ws = (char*)d_ws;
    size_t off = 0;
    _Float16* Wt2h = (_Float16*)(ws + off);
    off += (size_t)D_DIM * H_DIM * sizeof(_Float16);
    off = (off + 255) & ~(size_t)255;
    _Float16* VB = (_Float16*)(ws + off);
    off += (size_t)D_DIM * 32 * 64 * 8 * sizeof(_Float16);
    off = (off + 255) & ~(size_t)255;
    _Float16* PA = (_Float16*)(ws + off);

    k_prep2<<<dim3(PSCAN_BLKS + VPREP_BLKS + WPREP_BLKS), 256, 0, stream>>>(W, V, c, x, Wt2h, VB, PA);
    k_main<<<dim3(B_DIM / BT, T_CH), 256, 0, stream>>>(VB, Wt2h, PA, x, bias, out);
}

// Round 4
// 191.948 us; speedup vs baseline: 1.3092x; 1.3092x over previous
//
#include <hip/hip_runtime.h>
#include <stdint.h>

#define D_DIM 784
#define H_DIM 1024
#define B_DIM 256
#define NBIN  10
#define G_CH  8             // chunk length (i's per main block)
#define T_CH  98            // D_DIM / G_CH
#define BT    16            // batch tile per main block (fixed by MFMA M=16)
#define LOG2E 1.4426950408889634f

#define VPREP_BLKS D_DIM    // 784
#define WPREP_BLKS 208      // 13 * 16 tiles of W transpose

typedef _Float16 half8_t  __attribute__((ext_vector_type(8)));
typedef __fp16   fp16x2_t __attribute__((ext_vector_type(2)));
typedef float    float4_t __attribute__((ext_vector_type(4)));

// ---------------------------------------------------------------------------
// k_prep: V -> VB MFMA-fragment reshape (blocks [0,784)) and
//         W -> Wt2h f16 transpose x LOG2E (blocks [784,992)).
// Both jobs fully coalesced; 20 KB smem -> 8 blocks/CU.
// ---------------------------------------------------------------------------
__global__ void k_prep(const float* __restrict__ W, const float* __restrict__ V,
                       _Float16* __restrict__ Wt2h, _Float16* __restrict__ VB) {
    __shared__ __align__(16) float smem[5120];   // 20 KB
    int tid = threadIdx.x;
    int bx  = blockIdx.x;

    if (bx < VPREP_BLKS) {
        // ---- V -> VB fragment reshape, 2 passes of 512 h (20 KB each) ----
        int i = bx;
        const float4* src = (const float4*)(V + (size_t)i * H_DIM * NBIN);
        uint4* dst = (uint4*)VB + (size_t)i * 2048;
        #pragma unroll
        for (int p = 0; p < 2; ++p) {
            if (p) __syncthreads();               // pass-0 consumers done
            #pragma unroll
            for (int qv = 0; qv < 5; ++qv) {
                float4 v = src[p * 1280 + qv * 256 + tid];
                *((float4*)&smem[(qv * 256 + tid) * 4]) = v;
            }
            __syncthreads();
            #pragma unroll
            for (int qv = 0; qv < 4; ++qv) {
                int pair = p * 1024 + qv * 256 + tid;  // (kk,l) pair
                int kk = pair >> 6, ll = pair & 63;
                int n = ll & 15, hb = kk * 32 + ((ll >> 4) & 3) * 8;
                union { _Float16 hh[8]; uint4 u; } o;
                #pragma unroll
                for (int jj = 0; jj < 8; ++jj)
                    o.hh[jj] = (_Float16)((n < NBIN) ? smem[(hb + jj) * NBIN + n - p * 5120] : 0.0f);
                dst[pair] = o.u;
            }
        }
    } else {
        // ---- W transpose -> Wt2h (f16, x LOG2E) ----
        int qw = bx - VPREP_BLKS;               // 0..207
        int j0 = (qw % 13) * 64, h0 = (qw / 13) * 64;
        float (*t)[65] = (float(*)[65])smem;    // 16.6 KB view
        int tj = tid & 63, tr = tid >> 6;
        int j = j0 + tj;
        #pragma unroll
        for (int r = 0; r < 16; ++r) {
            int hh = tr * 16 + r;
            t[hh][tj] = (j < D_DIM) ? W[(size_t)(h0 + hh) * D_DIM + j] : 0.0f;
        }
        __syncthreads();
        #pragma unroll
        for (int r = 0; r < 16; ++r) {
            int jj = tr * 16 + r;
            int jo = j0 + jj;
            if (jo < D_DIM) Wt2h[(size_t)jo * H_DIM + h0 + tj] = (_Float16)(t[tj][jj] * LOG2E);
        }
    }
}

// ---------------------------------------------------------------------------
// k_pscan: prefix-scan PA from the TRANSPOSED Wt2h -> fully coalesced.
// Grid (256 b, 2 hg); thread owns 2 adjacent h (one uint of Wt2h / PA).
// Per t: 8 coalesced uint loads (256 B/wave each), 16 FMA, 1 packed store.
// Distance-1 register prefetch (static wvA/wvB double buffer); store issued
// before FMA so the exclusive-scan semantics hold and vmcnt never drains.
// ---------------------------------------------------------------------------
__global__ __launch_bounds__(256)
void k_pscan(const _Float16* __restrict__ Wt2h, const int* __restrict__ x,
             const float* __restrict__ c, _Float16* __restrict__ PA) {
    int b   = blockIdx.x;
    int hg  = blockIdx.y;
    int tid = threadIdx.x;
    int hcol = hg * 256 + tid;        // uint column 0..511
    int h0   = hcol * 2;

    __shared__ float xs[D_DIM];
    if (tid < D_DIM / 4) {
        int4 xi = ((const int4*)(x + (size_t)b * D_DIM))[tid];
        *((float4*)&xs[tid * 4]) =
            make_float4((float)xi.x, (float)xi.y, (float)xi.z, (float)xi.w);
    }
    float acc0 = c[h0] * LOG2E, acc1 = c[h0 + 1] * LOG2E;
    __syncthreads();

    const uint* wp  = (const uint*)Wt2h;   // [784][512] uints, h-contiguous
    uint*       pau = (uint*)PA;

    uint wvA[8], wvB[8];
    auto ldrow = [&](int t, uint (&wv)[8]) {
        #pragma unroll
        for (int r = 0; r < 8; ++r)
            wv[r] = wp[(size_t)(t * 8 + r) * 512 + hcol];
    };
    auto emit = [&](int t) {
        union { _Float16 hh[2]; uint u; } uu;
        uu.hh[0] = (_Float16)acc0; uu.hh[1] = (_Float16)acc1;
        pau[((size_t)t * B_DIM + b) * 512 + hcol] = uu.u;
    };
    auto fmas = [&](int t, const uint (&wv)[8]) {
        #pragma unroll
        for (int r = 0; r < 8; ++r) {
            union { uint u; _Float16 hh[2]; } uu; uu.u = wv[r];
            float xf = xs[t * 8 + r];
            acc0 += xf * (float)uu.hh[0];
            acc1 += xf * (float)uu.hh[1];
        }
    };

    ldrow(0, wvA);
    for (int t = 0; t < T_CH; t += 2) {
        ldrow(t + 1, wvB);            // prefetch odd row-group
        emit(t);
        fmas(t, wvA);
        if (t + 2 < T_CH) ldrow(t + 2, wvA);   // prefetch next even group
        emit(t + 1);
        fmas(t + 1, wvB);
    }
}

// ---------------------------------------------------------------------------
// main fused kernel: rolling 3-slot VB prefetch, streamed cf flush (low VGPR),
// launch_bounds(256,4). UNCHANGED for attribution (3rd round).
// ---------------------------------------------------------------------------
__global__ __launch_bounds__(256, 4)
void k_main(const _Float16* __restrict__ VB, const _Float16* __restrict__ Wt2h,
            const _Float16* __restrict__ PA, const int* __restrict__ x,
            const float* __restrict__ bias, float* __restrict__ out) {
    int bt  = blockIdx.x;        // batch tile 0..15 (fast dim: VB L2 reuse)
    int tc  = blockIdx.y;        // chunk 0..97
    int tid = threadIdx.x;
    int w   = tid >> 6;          // wave 0..3 (K-split of H)
    int l   = tid & 63;
    int bl  = l & 15;            // MFMA A row == batch row within tile
    int kg  = l >> 4;            // 0..3
    int bg  = bt * BT + bl;
    int i0  = tc * G_CH;

    __shared__ __align__(16) _Float16 wlds[G_CH][H_DIM]; // 16 KB
    __shared__ float red[4][64][18];                     // 18.4 KB, stride-18: 2-way max (free)
    __shared__ float bs[G_CH][16];                       // 0.5 KB

    {   // stage bias chunk
        int ii = tid >> 4, n = tid & 15;
        if (ii < G_CH) bs[ii][n] = (n < NBIN) ? bias[(size_t)(i0 + ii) * NBIN + n] : 0.0f;
    }
    {   // stage Wt2h chunk rows i0..i0+7 (f16 direct copy, coalesced)
        #pragma unroll
        for (int r = 0; r < G_CH; ++r) {
            uint2 v = ((const uint2*)(Wt2h + (size_t)(i0 + r) * H_DIM))[tid];
            *((uint2*)&wlds[r][tid * 4]) = v;
        }
    }
    float xvf[G_CH];
    {
        const int4* xp = (const int4*)(x + (size_t)bg * D_DIM + i0);
        int4 x0 = xp[0], x1 = xp[1];
        xvf[0] = (float)x0.x; xvf[1] = (float)x0.y; xvf[2] = (float)x0.z; xvf[3] = (float)x0.w;
        xvf[4] = (float)x1.x; xvf[5] = (float)x1.y; xvf[6] = (float)x1.z; xvf[7] = (float)x1.w;
    }
    float a[8][8];
    {
        const _Float16* src = PA + ((size_t)tc * B_DIM + bg) * H_DIM + w * 256 + kg * 8;
        #pragma unroll
        for (int m = 0; m < 8; ++m) {
            half8_t av = *((const half8_t*)(src + m * 32));
            #pragma unroll
            for (int j = 0; j < 8; ++j) a[m][j] = (float)av[j];
        }
    }

    // rolling 3-slot VB prefetch: slot mm%3 used at step mm, refilled for mm+2
    const uint4* vp = (const uint4*)VB + ((size_t)i0 * 32 + w * 8) * 64 + l;
    uint4 vbuf[3];
    vbuf[0] = vp[0];                 // (ii=0, m=0)
    vbuf[1] = vp[64];                // (ii=0, m=1)
    float4_t acc = {0.f, 0.f, 0.f, 0.f};

    auto step = [&](int mm) {        // mm = ii*8 + m, all indices static after unroll
        const int ii = mm >> 3, m = mm & 7;
        if (mm + 2 < 64) {
            const int nn = mm + 2;
            vbuf[nn % 3] = vp[((nn >> 3) * 32 + (nn & 7)) * 64];
        }
        union { half8_t h8; uint u32[4]; } af;
        #pragma unroll
        for (int p = 0; p < 4; ++p) {
            float s0 = __builtin_amdgcn_rcpf(1.0f + __builtin_amdgcn_exp2f(-a[m][2 * p]));
            float s1 = __builtin_amdgcn_rcpf(1.0f + __builtin_amdgcn_exp2f(-a[m][2 * p + 1]));
            union { fp16x2_t v; uint u; } cv;
            cv.v = __builtin_amdgcn_cvt_pkrtz(s0, s1);
            af.u32[p] = cv.u;
        }
        union { half8_t h8; uint4 u; } bf;
        bf.u = vbuf[mm % 3];
        acc = __builtin_amdgcn_mfma_f32_16x16x32_f16(af.h8, bf.h8, acc, 0, 0, 0);
        half8_t wh = *((const half8_t*)&wlds[ii][w * 256 + kg * 8 + m * 32]);
        float xf = xvf[ii];
        a[m][0] += xf * (float)wh[0]; a[m][1] += xf * (float)wh[1];
        a[m][2] += xf * (float)wh[2]; a[m][3] += xf * (float)wh[3];
        a[m][4] += xf * (float)wh[4]; a[m][5] += xf * (float)wh[5];
        a[m][6] += xf * (float)wh[6]; a[m][7] += xf * (float)wh[7];
        if (m == 7) {                // stream flush: keeps only ONE float4 acc live
            int s = (ii & 3) * 4;
            red[w][l][s + 0] = acc[0]; red[w][l][s + 1] = acc[1];
            red[w][l][s + 2] = acc[2]; red[w][l][s + 3] = acc[3];
            acc = (float4_t){0.f, 0.f, 0.f, 0.f};
        }
    };

    auto softmax_store = [&](int half) {
        float p4[4];
        #pragma unroll
        for (int q = 0; q < 4; ++q) {
            int ii = half * 4 + q;
            float tot = red[0][l][q * 4 + w] + red[1][l][q * 4 + w]
                      + red[2][l][q * 4 + w] + red[3][l][q * 4 + w];
            float v = (bl < NBIN) ? tot + bs[ii][bl] : -3.0e38f;
            float vm = v;
            vm = fmaxf(vm, __shfl_xor(vm, 1));
            vm = fmaxf(vm, __shfl_xor(vm, 2));
            vm = fmaxf(vm, __shfl_xor(vm, 4));
            vm = fmaxf(vm, __shfl_xor(vm, 8));
            float e = __builtin_amdgcn_exp2f((v - vm) * LOG2E);
            float ss = e;
            ss += __shfl_xor(ss, 1); ss += __shfl_xor(ss, 2);
            ss += __shfl_xor(ss, 4); ss += __shfl_xor(ss, 8);
            p4[q] = e * __builtin_amdgcn_rcpf(ss);
        }
        if (bl < NBIN) {
            int b = bt * BT + kg * 4 + w;   // this thread's C row = batch row
            size_t base = ((size_t)b * NBIN + bl) * D_DIM + i0 + half * 4;
            float4 v = make_float4(p4[0], p4[1], p4[2], p4[3]);
            *((float4*)(out + base)) = v;
        }
    };

    __syncthreads();               // B0: wlds/bs staged
    #pragma unroll
    for (int mm = 0; mm < 32; ++mm) step(mm);     // half 0 (red streamed)
    __syncthreads();               // B1: half-0 partials visible
    softmax_store(0);
    __syncthreads();               // B2: all half-0 reads done
    #pragma unroll
    for (int mm = 32; mm < 64; ++mm) step(mm);    // half 1 (red streamed)
    __syncthreads();               // B3: half-1 partials visible
    softmax_store(1);
}

extern "C" void kernel_launch(void* const* d_in, const int* in_sizes, int n_in,
                              void* d_out, int out_size, void* d_ws, size_t ws_size,
                              hipStream_t stream) {
    const int*   x    = (const int*)d_in[0];
    const float* W    = (const float*)d_in[1];
    const float* c    = (const float*)d_in[2];
    const float* V    = (const float*)d_in[3];
    const float* bias = (const float*)d_in[4];
    float* out = (float*)d_out;

    char* ws = (char*)d_ws;
    size_t off = 0;
    _Float16* Wt2h = (_Float16*)(ws + off);
    off += (size_t)D_DIM * H_DIM * sizeof(_Float16);
    off = (off + 255) & ~(size_t)255;
    _Float16* VB = (_Float16*)(ws + off);
    off += (size_t)D_DIM * 32 * 64 * 8 * sizeof(_Float16);
    off = (off + 255) & ~(size_t)255;
    _Float16* PA = (_Float16*)(ws + off);

    k_prep<<<dim3(VPREP_BLKS + WPREP_BLKS), 256, 0, stream>>>(W, V, Wt2h, VB);
    k_pscan<<<dim3(B_DIM, 2), 256, 0, stream>>>(Wt2h, x, c, PA);
    k_main<<<dim3(B_DIM / BT, T_CH), 256, 0, stream>>>(VB, Wt2h, PA, x, bias, out);
}